// Round 5
// baseline (165.232 us; speedup 1.0000x reference)
//
#include <hip/hip_runtime.h>

// Problem constants (fixed by the reference setup)
#define B_ 64
#define T_ 32
#define H_ 256
#define NMAX_ 64
#define GRID 1024    // 1024 blocks x 2 tiles = 2048 tiles (64 rows x 256 cols each)
#define BLOCK 512    // 8 waves; wave owns 32 output cols (MFMA) and 8 L1 rows
#define HSROW 136    // Hs row stride in shorts (272B rows; proven 0-conflict layout)

typedef __attribute__((ext_vector_type(8))) short short8;  // 8 bf16 = 4 VGPRs
typedef __attribute__((ext_vector_type(4))) float f32x4;   // MFMA C/D frag

// float -> bf16 bits, round-to-nearest-even (values are finite here)
__device__ __forceinline__ unsigned f2bfbits(float f) {
    unsigned u = __builtin_bit_cast(unsigned, f);
    return (u + 0x7fffu + ((u >> 16) & 1u)) >> 16;
}

// Workgroup barrier WITHOUT the vmcnt(0) store drain __syncthreads would emit.
// LDS visibility needs only lgkmcnt(0); global stores are fire-and-forget.
__device__ __forceinline__ void barrier_nodrain() {
    asm volatile("s_waitcnt lgkmcnt(0)\n\ts_barrier" ::: "memory");
}

// 4 waves/SIMD -> VGPR cap 128 (est ~118). LDS ~19KB -> 2 blocks/CU, 16 waves/CU.
__global__ __launch_bounds__(BLOCK, 4)
void pe_fused(const float* __restrict__ bbox,
              const float* __restrict__ W1,
              const float* __restrict__ b1,
              const float* __restrict__ W2,
              const float* __restrict__ b2,
              const int*   __restrict__ npf,
              float* __restrict__ out,
              int NT)   // total bbox rows = N*T
{
    __shared__ int   s_n[64];
    __shared__ int   s_start[64];
    __shared__ short Hs[64 * HSROW];   // 64 rows x 128 bf16 hidden (single buffer)

    const int tid  = threadIdx.x;
    const int wave = tid >> 6;    // 0..7
    const int lane = tid & 63;
    const int q    = lane >> 4;   // quad within wave
    const int m16  = lane & 15;

    // Exclusive prefix sum of npf via wave-0 shuffle scan.
    if (wave == 0) {
        int v = npf[lane];
        s_n[lane] = v;
        int s = v;
#pragma unroll
        for (int d = 1; d < 64; d <<= 1) {
            int u = __shfl_up(s, d, 64);
            if (lane >= d) s += u;
        }
        s_start[lane] = s - v;
    }

    // ---- Per-thread L1 state: W1 column PAIR h0 = lane*2 (10 VGPRs, loaded once).
    const int h0 = lane * 2;
    float w1a[4], w1b[4];
#pragma unroll
    for (int x = 0; x < 4; ++x) {
        w1a[x] = W1[x * 128 + h0];
        w1b[x] = W1[x * 128 + h0 + 1];
    }
    const float b1a = b1[h0], b1b = b1[h0 + 1];

    // W2^T fragments (A operand) in registers, bf16. Wave w owns cols [32w, 32w+32).
    const int colw = wave * 32;
    short8 Wf[2][4];
#pragma unroll
    for (int ct = 0; ct < 2; ++ct)
#pragma unroll
        for (int kc = 0; kc < 4; ++kc) {
            const int k0 = kc * 32 + q * 8;
            short8 f;
#pragma unroll
            for (int jj = 0; jj < 8; ++jj)
                f[jj] = (short)f2bfbits(W2[(k0 + jj) * H_ + colw + ct * 16 + m16]);
            Wf[ct][kc] = f;
        }
    // b2 quads straight from global (L2-hot, once); bias folded into acc init.
    float4 bq[2];
#pragma unroll
    for (int ct = 0; ct < 2; ++ct)
        bq[ct] = *(const float4*)(b2 + colw + ct * 16 + q * 4);

    __syncthreads();   // s_n/s_start ready

#pragma unroll
    for (int i = 0; i < 2; ++i) {
        const int tt = blockIdx.x + i * GRID;
        const int b  = tt >> 5;
        const int l0 = (tt & 31) * 2;
        const int nb = s_n[b];

        const int ob0 = (l0 * (B_ * T_) + b * T_) * H_;  // out row (l0,  b, t=0)
        const int ob1 = ob0 + (B_ * T_) * H_;            // out row (l0+1,b, t=0)

        if (l0 >= nb) {
            // Whole tile invalid (block-uniform): zero-fill 64 rows x 1KB,
            // one store instr = one contiguous 1KB row (full-line requests).
            const float4 z = make_float4(0.f, 0.f, 0.f, 0.f);
#pragma unroll
            for (int rr = 0; rr < 8; ++rr) {
                const int r = wave * 8 + rr;   // wave-uniform row 0..63
                float* dst = out + (r < 32 ? ob0 + r * H_ : ob1 + (r - 32) * H_);
                *(float4*)(dst + lane * 4) = z;
            }
            continue;   // block-uniform branch; no LDS / barriers on this path
        }

        // ---- Layer 1: wave w computes rows [8w, 8w+8), thread computes its h-pair.
        // 8 broadcast float4 loads + ~14 VALU/row + 8 conflict-free ds_write_b32.
        {
            const int gbase = (s_start[b] + l0) * T_ + wave * 8;
            float4 bx[8];
#pragma unroll
            for (int k = 0; k < 8; ++k) {
                const int g = gbase + k;   // guard: b=63 tail can run past NT
                bx[k] = make_float4(0.f, 0.f, 0.f, 0.f);
                if (g < NT) bx[k] = *(const float4*)(bbox + g * 4);
            }
#pragma unroll
            for (int k = 0; k < 8; ++k) {
                const float4 bv = bx[k];
                float va = b1a, vb = b1b;
                va = fmaf(bv.x, w1a[0], va); vb = fmaf(bv.x, w1b[0], vb);
                va = fmaf(bv.y, w1a[1], va); vb = fmaf(bv.y, w1b[1], vb);
                va = fmaf(bv.z, w1a[2], va); vb = fmaf(bv.z, w1b[2], vb);
                va = fmaf(bv.w, w1a[3], va); vb = fmaf(bv.w, w1b[3], vb);
                va = fmaxf(va, 0.f);         vb = fmaxf(vb, 0.f);
                const unsigned packed = f2bfbits(va) | (f2bfbits(vb) << 16);
                // byte addr = row*272 + lane*4 -> consecutive dwords, 2-way = free
                *(unsigned*)&Hs[(wave * 8 + k) * HSROW + h0] = packed;
            }
        }
        barrier_nodrain();   // B1: Hs ready

        // ---- Layer 2 (transposed orientation): D[m=h][n=row] = W2^T x H^T ----
        f32x4 acc[2][4];   // [ct][rt], bias-initialized
#pragma unroll
        for (int ct = 0; ct < 2; ++ct)
#pragma unroll
            for (int rt = 0; rt < 4; ++rt)
                acc[ct][rt] = (f32x4){bq[ct].x, bq[ct].y, bq[ct].z, bq[ct].w};

#pragma unroll
        for (int kc = 0; kc < 4; ++kc) {
            short8 hf[4];
#pragma unroll
            for (int rt = 0; rt < 4; ++rt)  // B-operand: H[n=rt*16+m16][k0..k0+7]
                hf[rt] = *(const short8*)&Hs[(rt * 16 + m16) * HSROW + kc * 32 + q * 8];
#pragma unroll
            for (int ct = 0; ct < 2; ++ct)
#pragma unroll
                for (int rt = 0; rt < 4; ++rt)
                    acc[ct][rt] = __builtin_amdgcn_mfma_f32_16x16x32_bf16(
                        Wf[ct][kc], hf[rt], acc[ct][rt], 0, 0, 0);
        }
        barrier_nodrain();   // B2: all waves' Hs reads done before next tile's L1

        // ---- Direct stores, 128B-sector-paired: per (rt, row) the wave's two
        // back-to-back dwordx4 (ct=0,1) cover cols [colw, colw+32) = one full
        // contiguous 128B sector; 8 waves tile the 1KB row.
        const bool v1 = (l0 + 1) < nb;   // block-uniform
#pragma unroll
        for (int rt = 0; rt < 4; ++rt) {
            const int t = (rt & 1) * 16 + m16;
            float* dst = out + (rt < 2 ? ob0 : ob1) + t * H_ + colw + q * 4;
            if (rt >= 2 && !v1) {
                const float4 z = make_float4(0.f, 0.f, 0.f, 0.f);
                *(float4*)dst = z;
                *(float4*)(dst + 16) = z;
            } else {
                const f32x4 a0 = acc[0][rt];
                const f32x4 a1 = acc[1][rt];
                *(float4*)dst        = make_float4(a0[0], a0[1], a0[2], a0[3]);
                *(float4*)(dst + 16) = make_float4(a1[0], a1[1], a1[2], a1[3]);
            }
        }
    }
}

extern "C" void kernel_launch(void* const* d_in, const int* in_sizes, int n_in,
                              void* d_out, int out_size, void* d_ws, size_t ws_size,
                              hipStream_t stream)
{
    const float* bbox = (const float*)d_in[0];
    const float* W1   = (const float*)d_in[1];
    const float* b1   = (const float*)d_in[2];
    const float* W2   = (const float*)d_in[3];
    const float* b2   = (const float*)d_in[4];
    const int*   npf  = (const int*)d_in[5];
    const int NT = in_sizes[0] / 4;  // N*T

    pe_fused<<<GRID, BLOCK, 0, stream>>>(bbox, W1, b1, W2, b2, npf,
                                         (float*)d_out, NT);
}